// Round 10
// baseline (331.141 us; speedup 1.0000x reference)
//
#include <hip/hip_runtime.h>
#include <hip/hip_bf16.h>

typedef __hip_bfloat16 bfloat;
typedef __bf16 bf16x8 __attribute__((ext_vector_type(8)));
typedef float f32x4 __attribute__((ext_vector_type(4)));

#define B_SZ   16384
#define E_DIM  128
#define HIST_L 50

// DTYPE MAP (rounds 0-4): inputs fp32, output fp32, internal bf16 for MFMA.
// WS DISCIPLINE (round 4): chunked batch, strictly inside ws_size
//   (ws in [31.37, 56.77) MB per rounds 5/7 ladder evidence).
// ROUND 9 pm: DMA staging + stride-32 gave 93.6->85us MLP1 (conflicts halved
// exactly = the ds_writes). But occupancy stuck at 37%: grid 512 blocks =
// 2 blocks/CU, 8/32 waves — each K-iter barrier drains DMA with nothing
// co-resident to overlap. LDS reads 17%, conflicts 11%, MFMA 2.5% of cycles:
// parallelism-bound, not pipe-bound.
// ROUND 10: (a) M-split — MT=64 tiles for MLP1/xw (1024 blocks = 4/CU,
// 16 waves/CU; no atomics needed, unlike split-K); (b) pair product via
// __hmul2 packed bf16 (v_pk_mul path) to cut staging VALU.

// compact pair tables (pp=0..9 <-> orig pairs (1,2),(1,3),(1,4),(1,5),
// (2,3),(2,4),(2,5),(3,4),(3,5),(4,5)); xs slot = I-1, xw slot = J-2.
#define IPACK 0x3221110000ULL
#define JPACK 0x3323213210ULL

__device__ __forceinline__ void gl_lds16(const void* g, void* l) {
    __builtin_amdgcn_global_load_lds(
        (const __attribute__((address_space(1))) unsigned int*)g,
        (__attribute__((address_space(3))) unsigned int*)l, 16, 0, 0);
}

__device__ __forceinline__ bf16x8 mul_bf16x8(bf16x8 a, bf16x8 b) {
    union { bf16x8 v; __hip_bfloat162 h[4]; } ua, ub, ur;
    ua.v = a; ub.v = b;
    #pragma unroll
    for (int i = 0; i < 4; ++i) ur.h[i] = __hmul2(ua.h[i], ub.h[i]);
    return ur.v;
}

// ---------------------------------------------------------------- features
// 256 threads = 2 batch rows per block. mm (post-bias fp32) precomputed.
__global__ __launch_bounds__(256) void feat_kernel(
    const int* __restrict__ item_id,
    const int* __restrict__ likes, const int* __restrict__ views,
    const int* __restrict__ seq,
    const float* __restrict__ item_emb, const float* __restrict__ cate_emb,
    const float* __restrict__ mm,
    const float* __restrict__ ln_g, const float* __restrict__ ln_b,
    const float* __restrict__ se_W1, const float* __restrict__ se_b1,
    const float* __restrict__ se_W2, const float* __restrict__ se_b2,
    bfloat* __restrict__ xs)
{
    const int tid = threadIdx.x;
    const int r   = tid >> 7;            // sub-row 0/1
    const int e   = tid & 127;
    const int b   = blockIdx.x * 2 + r;
    const int w   = tid >> 6;            // wave 0..3 (row = w>>1)

    __shared__ float redh[2][4][128];
    __shared__ int   seq_s[2][64];
    __shared__ float lnred[4], lnred2[4];
    __shared__ float zred[5][4];
    __shared__ float wsh[2][6];
    __shared__ int   cnt_s[2];

    if (e < 64) seq_s[r][e] = (e < HIST_L) ? seq[(size_t)b * HIST_L + e] : 0;
    __syncthreads();

    // long-latency gathers first
    const int iid = item_id[b];
    const float like_v = cate_emb[likes[b] * 128 + e];
    const float view_v = cate_emb[views[b] * 128 + e];
    const float item_raw = item_emb[(size_t)iid * 128 + e];
    const float item_v = iid ? item_raw : 0.f;
    const float acc = mm[(size_t)b * 128 + e];   // bias already added

    const int q   = e >> 5;
    const int l32 = e & 31;
    float4 hs = make_float4(0.f, 0.f, 0.f, 0.f);
    #pragma unroll
    for (int g = 0; g < 13; ++g) {
        int s = seq_s[r][g * 4 + q];
        const float4 v = *(const float4*)&item_emb[(size_t)s * 128 + l32 * 4];
        float m = (s != 0) ? 1.f : 0.f;
        hs.x = fmaf(v.x, m, hs.x);
        hs.y = fmaf(v.y, m, hs.y);
        hs.z = fmaf(v.z, m, hs.z);
        hs.w = fmaf(v.w, m, hs.w);
    }

    // LayerNorm reductions (per 2-wave row)
    {
        float v = acc;
        #pragma unroll
        for (int off = 32; off > 0; off >>= 1) v += __shfl_down(v, off, 64);
        if ((tid & 63) == 0) lnred[w] = v;
    }
    __syncthreads();
    const float mu = (lnred[2 * r] + lnred[2 * r + 1]) * (1.f / 128.f);
    const float d  = acc - mu;
    {
        float v = d * d;
        #pragma unroll
        for (int off = 32; off > 0; off >>= 1) v += __shfl_down(v, off, 64);
        if ((tid & 63) == 0) lnred2[w] = v;
    }
    redh[r][q][l32 * 4 + 0] = hs.x;
    redh[r][q][l32 * 4 + 1] = hs.y;
    redh[r][q][l32 * 4 + 2] = hs.z;
    redh[r][q][l32 * 4 + 3] = hs.w;
    if ((w & 1) == 0 && e < 64) {       // first wave of each row
        bool valid = (e < HIST_L) && (seq_s[r][e] != 0);
        unsigned long long m = __ballot(valid);
        if (e == 0) cnt_s[r] = (int)__popcll(m);
    }
    __syncthreads();
    const float var = (lnred2[2 * r] + lnred2[2 * r + 1]) * (1.f / 128.f);
    float xmm = d * rsqrtf(var + 1e-5f) * ln_g[e] + ln_b[e];
    xmm = fmaxf(xmm, 0.f);

    const int cnt = cnt_s[r] > 0 ? cnt_s[r] : 1;
    const float hist_v = (redh[r][0][e] + redh[r][1][e] +
                          redh[r][2][e] + redh[r][3][e]) / (float)cnt;

    // SENet z means: 5 sums, one barrier
    {
        float s1 = like_v, s2 = view_v, s3 = item_v, s4 = xmm, s5 = hist_v;
        #pragma unroll
        for (int off = 32; off > 0; off >>= 1) {
            s1 += __shfl_down(s1, off, 64);
            s2 += __shfl_down(s2, off, 64);
            s3 += __shfl_down(s3, off, 64);
            s4 += __shfl_down(s4, off, 64);
            s5 += __shfl_down(s5, off, 64);
        }
        if ((tid & 63) == 0) {
            zred[0][w] = s1; zred[1][w] = s2; zred[2][w] = s3;
            zred[3][w] = s4; zred[4][w] = s5;
        }
    }
    __syncthreads();

    if (e == 0) {
        float z[6];
        z[0] = 0.f;
        #pragma unroll
        for (int f = 1; f < 6; ++f)
            z[f] = (zred[f - 1][2 * r] + zred[f - 1][2 * r + 1]) * (1.f / 128.f);
        float a[3];
        #pragma unroll
        for (int j = 0; j < 3; ++j) {
            float s = se_b1[j];
            #pragma unroll
            for (int f = 0; f < 6; ++f) s += z[f] * se_W1[f * 3 + j];
            a[j] = fmaxf(s, 0.f);
        }
        #pragma unroll
        for (int f = 0; f < 6; ++f) {
            float s = se_b2[f];
            #pragma unroll
            for (int j = 0; j < 3; ++j) s += a[j] * se_W2[j * 6 + f];
            wsh[r][f] = 1.f / (1.f + expf(-s));
        }
    }
    __syncthreads();

    bfloat* xrow = xs + (size_t)b * 640;      // fields 1..5 at slots 0..4
    xrow[0 * 128 + e] = __float2bfloat16(like_v * wsh[r][1]);
    xrow[1 * 128 + e] = __float2bfloat16(view_v * wsh[r][2]);
    xrow[2 * 128 + e] = __float2bfloat16(item_v * wsh[r][3]);
    xrow[3 * 128 + e] = __float2bfloat16(xmm    * wsh[r][4]);
    xrow[4 * 128 + e] = __float2bfloat16(hist_v * wsh[r][5]);
}

// ---------------------------------------------------------------- transposes
__global__ __launch_bounds__(256) void transpose_f32_bf16(
    const float* __restrict__ in, bfloat* __restrict__ out, int K, int N)
{
    int idx = blockIdx.x * 256 + threadIdx.x;
    if (idx < K * N) {
        int k = idx / N, n = idx % N;
        out[(size_t)n * K + k] = __float2bfloat16(in[idx]);
    }
}

// W1 compact transpose: W1t[n][kk] = W1[orig(kk)][n], orig = kk + (kk<640?128:768)
__global__ __launch_bounds__(256) void transpose_W1c(
    const float* __restrict__ W1, bfloat* __restrict__ W1t)
{
    int idx = blockIdx.x * 256 + threadIdx.x;
    if (idx < 512 * 1920) {
        int n = idx / 1920, kk = idx % 1920;
        int orig = kk + (kk < 640 ? 128 : 768);
        W1t[idx] = __float2bfloat16(W1[(size_t)orig * 512 + n]);
    }
}

// BN folding + mm-bias copy.
__global__ __launch_bounds__(256) void bn_pre(
    const float* __restrict__ lb1, const float* __restrict__ g1,
    const float* __restrict__ bb1, const float* __restrict__ rm1,
    const float* __restrict__ rv1,
    const float* __restrict__ lb2, const float* __restrict__ g2,
    const float* __restrict__ bb2, const float* __restrict__ rm2,
    const float* __restrict__ rv2,
    const float* __restrict__ mm_b,
    float* __restrict__ S1, float* __restrict__ T1,
    float* __restrict__ S2, float* __restrict__ T2,
    float* __restrict__ Tmm)
{
    int j = blockIdx.x * 256 + threadIdx.x;
    if (j < 512) {
        float s = g1[j] * rsqrtf(rv1[j] + 1e-5f);
        S1[j] = s;
        T1[j] = (lb1[j] - rm1[j]) * s + bb1[j];
    } else if (j < 768) {
        int k = j - 512;
        float s = g2[k] * rsqrtf(rv2[k] + 1e-5f);
        S2[k] = s;
        T2[k] = (lb2[k] - rm2[k]) * s + bb2[k];
    } else if (j < 896) {
        Tmm[j - 768] = mm_b[j - 768];
    }
}

// ---------------------------------------------------------------- MFMA GEMM
// C(M,N) = A(M,K) @ Bt(N,K)^T.  Tile MT x NT, BK=32, 256 threads = 4 waves
// arranged 2x2 over (MT/2, NT/2).  MODE 0: plain bf16 A (async DMA).
// MODE 1: fused MLP1 (xs region DMA, pair region = __hmul2 product, K=1920).
// MODE 2: xw rows from xs (DMA).  MODE 3: A fp32 row-major, cvt in regs.
// B always async DMA. LDS stride 32 shorts (lane-contiguous = DMA layout).
// EPI 0: raw. EPI 1: relu(acc*S+T). EPI 2: acc+T. F32OUT: write fp32.
template<int MODE, int EPI, int MT, int NT, int F32OUT>
__global__ __launch_bounds__(256) void gemm_bt(
    const void* __restrict__ A, const bfloat* __restrict__ A2,
    const bfloat* __restrict__ Bt, void* __restrict__ C,
    int M, int N, int K,
    const float* __restrict__ S, const float* __restrict__ T)
{
    __shared__ __align__(16) short As[MT * 32];
    __shared__ __align__(16) short Bs[NT * 32];

    const int tid  = threadIdx.x;
    const int bm   = blockIdx.x * MT;
    const int bn   = blockIdx.y * NT;
    const int wave = tid >> 6;
    const int lane = tid & 63;
    const int wm   = (wave >> 1) * (MT / 2);
    const int wn   = (wave & 1) * (NT / 2);
    const int AF   = MT / 32;           // A frags per wave
    const int BF   = NT / 32;           // B frags per wave

    const short* Ag  = (const short*)A;
    const short* A2g = (const short*)A2;
    const short* Bg  = (const short*)Bt;

    f32x4 acc[MT / 32][NT / 32];
    #pragma unroll
    for (int i = 0; i < AF; ++i)
        #pragma unroll
        for (int j = 0; j < BF; ++j)
            acc[i][j] = (f32x4){0.f, 0.f, 0.f, 0.f};

    const int srow = tid >> 2;          // 0..63
    const int skc  = (tid & 3) * 8;     // k-chunk within tile

    for (int kt = 0; kt < K; kt += 32) {
        __syncthreads();
        // ---- A staging (MT rows; LDS dest tid*16 B = lane-contiguous) ----
        #pragma unroll
        for (int r = 0; r < MT / 64; ++r) {
            int row = srow + r * 64;
            short* dst = &As[row * 32 + skc];
            if (MODE == 1) {
                long rb = (long)(bm + row);
                if (kt < 640) {
                    gl_lds16(&Ag[rb * 640 + kt + skc], dst);
                } else {
                    int pp  = (kt - 640) >> 7;            // wave-uniform
                    int isl = (int)((IPACK >> (4 * pp)) & 15);
                    int jsl = (int)((JPACK >> (4 * pp)) & 15);
                    int e0  = ((kt - 640) & 127) + skc;
                    bf16x8 a = *(const bf16x8*)&Ag [rb * 640 + isl * 128 + e0];
                    bf16x8 b = *(const bf16x8*)&A2g[rb * 512 + jsl * 128 + e0];
                    *(bf16x8*)dst = mul_bf16x8(a, b);
                }
            } else if (MODE == 2) {
                int gr = bm + row;
                gl_lds16(&Ag[((long)(gr >> 2)) * 640 + ((gr & 3) + 1) * 128 +
                             kt + skc], dst);
            } else if (MODE == 3) {
                const float* Af = (const float*)A;
                long aoff = (long)(bm + row) * K + kt + skc;
                float4 f0 = *(const float4*)&Af[aoff];
                float4 f1 = *(const float4*)&Af[aoff + 4];
                union { bf16x8 v; unsigned short s[8]; } u;
                u.s[0] = __bfloat16_as_ushort(__float2bfloat16(f0.x));
                u.s[1] = __bfloat16_as_ushort(__float2bfloat16(f0.y));
                u.s[2] = __bfloat16_as_ushort(__float2bfloat16(f0.z));
                u.s[3] = __bfloat16_as_ushort(__float2bfloat16(f0.w));
                u.s[4] = __bfloat16_as_ushort(__float2bfloat16(f1.x));
                u.s[5] = __bfloat16_as_ushort(__float2bfloat16(f1.y));
                u.s[6] = __bfloat16_as_ushort(__float2bfloat16(f1.z));
                u.s[7] = __bfloat16_as_ushort(__float2bfloat16(f1.w));
                *(bf16x8*)dst = u.v;
            } else {
                gl_lds16(&Ag[(long)(bm + row) * K + kt + skc], dst);
            }
        }
        // ---- B staging (NT rows) via async DMA ----
        #pragma unroll
        for (int r = 0; r < NT / 64; ++r) {
            int row = srow + r * 64;
            gl_lds16(&Bg[(long)(bn + row) * K + kt + skc],
                     &Bs[row * 32 + skc]);
        }
        __syncthreads();

        const int koff  = (lane >> 4) * 8;
        const int rbase = lane & 15;
        bf16x8 af[MT / 32], bfr[NT / 32];
        #pragma unroll
        for (int mt = 0; mt < AF; ++mt)
            af[mt] = *(const bf16x8*)&As[(wm + mt * 16 + rbase) * 32 + koff];
        #pragma unroll
        for (int nt = 0; nt < BF; ++nt)
            bfr[nt] = *(const bf16x8*)&Bs[(wn + nt * 16 + rbase) * 32 + koff];
        #pragma unroll
        for (int mt = 0; mt < AF; ++mt)
            #pragma unroll
            for (int nt = 0; nt < BF; ++nt)
                acc[mt][nt] = __builtin_amdgcn_mfma_f32_16x16x32_bf16(
                    af[mt], bfr[nt], acc[mt][nt], 0, 0, 0);
    }

    // epilogue: C/D layout col = lane&15, row = (lane>>4)*4 + i
    const int col0 = lane & 15;
    const int row0 = (lane >> 4) * 4;
    #pragma unroll
    for (int nt = 0; nt < BF; ++nt) {
        int col = bn + wn + nt * 16 + col0;
        float s = 1.f, t = 0.f;
        if (EPI) { s = (EPI == 1) ? S[col] : 1.f; t = T[col]; }
        #pragma unroll
        for (int mt = 0; mt < AF; ++mt) {
            #pragma unroll
            for (int i = 0; i < 4; ++i) {
                int row = bm + wm + mt * 16 + row0 + i;
                float v = acc[mt][nt][i];
                if (EPI == 1) v = fmaxf(v * s + t, 0.f);
                if (EPI == 2) v = v + t;
                if (F32OUT) ((float*)C)[(size_t)row * N + col] = v;
                else ((bfloat*)C)[(size_t)row * N + col] = __float2bfloat16(v);
            }
        }
    }
}

// ---------------------------------------------------------------- head
__global__ __launch_bounds__(256) void head_kernel(
    const bfloat* __restrict__ h2, const float* __restrict__ W3,
    const float* __restrict__ b3, float* __restrict__ out)
{
    int lane = threadIdx.x & 63;
    int row  = blockIdx.x * 4 + (threadIdx.x >> 6);
    float acc = 0.f;
    #pragma unroll
    for (int i = 0; i < 4; ++i)
        acc += __bfloat162float(h2[(size_t)row * 256 + i * 64 + lane]) *
               W3[i * 64 + lane];
    #pragma unroll
    for (int off = 32; off > 0; off >>= 1) acc += __shfl_down(acc, off, 64);
    if (lane == 0) {
        float l = acc + b3[0];
        out[row] = 1.f / (1.f + expf(-l));
    }
}

// ---------------------------------------------------------------- launch
extern "C" void kernel_launch(void* const* d_in, const int* in_sizes, int n_in,
                              void* d_out, int out_size, void* d_ws, size_t ws_size,
                              hipStream_t stream) {
    const int*   item_id = (const int*)  d_in[0];
    const float* d128    = (const float*)d_in[1];
    const int*   likes   = (const int*)  d_in[2];
    const int*   views   = (const int*)  d_in[3];
    const int*   seq     = (const int*)  d_in[4];
    const float* item_emb= (const float*)d_in[5];
    const float* cate_emb= (const float*)d_in[6];
    const float* mm_W    = (const float*)d_in[7];
    const float* mm_b    = (const float*)d_in[8];
    const float* ln_g    = (const float*)d_in[9];
    const float* ln_b    = (const float*)d_in[10];
    const float* se_W1   = (const float*)d_in[11];
    const float* se_b1   = (const float*)d_in[12];
    const float* se_W2   = (const float*)d_in[13];
    const float* se_b2   = (const float*)d_in[14];
    const float* bi_W    = (const float*)d_in[15];
    const float* W1      = (const float*)d_in[16];
    const float* b1      = (const float*)d_in[17];
    const float* bn1_g   = (const float*)d_in[18];
    const float* bn1_b   = (const float*)d_in[19];
    const float* bn1_rm  = (const float*)d_in[20];
    const float* bn1_rv  = (const float*)d_in[21];
    const float* W2      = (const float*)d_in[22];
    const float* b2      = (const float*)d_in[23];
    const float* bn2_g   = (const float*)d_in[24];
    const float* bn2_b   = (const float*)d_in[25];
    const float* bn2_rm  = (const float*)d_in[26];
    const float* bn2_rv  = (const float*)d_in[27];
    const float* W3      = (const float*)d_in[28];
    const float* b3      = (const float*)d_in[29];

    // --------- workspace (ws_size in [31.4, 56.8) MB per rounds 5/7) --------
    // fixed: W1t 1,966,080 | W2t 262,144 | bWt 32,768 | mmWt 32,768 |
    //        S1/T1 4,096 | S2/T2 2,048 | Tmm 512  = 2,300,416 B
    // per-row 3328 B: xs 1280 | xw 1024 | h1 1024. h2 aliases xw;
    // mm (fp32, 512 B/row) aliases h1 (consumed by feat before h1 written).
    const size_t fixed = 2300416;
    int CH = 1024;
    if      (fixed + (size_t)16384 * 3328 <= ws_size) CH = 16384;
    else if (fixed + (size_t)8192  * 3328 <= ws_size) CH = 8192;
    else if (fixed + (size_t)4096  * 3328 <= ws_size) CH = 4096;
    else if (fixed + (size_t)2048  * 3328 <= ws_size) CH = 2048;

    char* ws = (char*)d_ws;
    bfloat* W1t = (bfloat*)(ws);                 // 1,966,080
    bfloat* W2t = (bfloat*)(ws + 1966080);       //   262,144
    bfloat* bWt = (bfloat*)(ws + 2228224);       //    32,768
    bfloat* mmWt= (bfloat*)(ws + 2260992);       //    32,768
    float*  S1  = (float*) (ws + 2293760);       //     2,048
    float*  T1  = (float*) (ws + 2295808);       //     2,048
    float*  S2  = (float*) (ws + 2297856);       //     1,024
    float*  T2  = (float*) (ws + 2298880);       //     1,024
    float*  Tmm = (float*) (ws + 2299904);       //       512 -> 2,300,416
    bfloat* xs  = (bfloat*)(ws + fixed);                        // CH*1280 B
    bfloat* xw  = (bfloat*)(ws + fixed + (size_t)CH * 1280);    // CH*1024 B
    bfloat* h1  = (bfloat*)(ws + fixed + (size_t)CH * 2304);    // CH*1024 B
    bfloat* h2  = xw;                                           // alias
    float*  mm  = (float*)h1;                                   // alias

    transpose_W1c<<<(512 * 1920 + 255) / 256, 256, 0, stream>>>(W1, W1t);
    transpose_f32_bf16<<<(512 * 256 + 255) / 256, 256, 0, stream>>>(W2, W2t, 512, 256);
    transpose_f32_bf16<<<(128 * 128 + 255) / 256, 256, 0, stream>>>(bi_W, bWt, 128, 128);
    transpose_f32_bf16<<<(128 * 128 + 255) / 256, 256, 0, stream>>>(mm_W, mmWt, 128, 128);
    bn_pre<<<4, 256, 0, stream>>>(b1, bn1_g, bn1_b, bn1_rm, bn1_rv,
                                  b2, bn2_g, bn2_b, bn2_rm, bn2_rv,
                                  mm_b, S1, T1, S2, T2, Tmm);

    for (int off = 0; off < B_SZ; off += CH) {
        // mm = d128 @ mm_W + b  (fp32 out; aliases h1, consumed by feat)
        dim3 gmm(CH / 64, 128 / 64);
        gemm_bt<3, 2, 64, 64, 1><<<gmm, 256, 0, stream>>>(
            d128 + (size_t)off * 128, nullptr, mmWt, mm,
            CH, 128, 128, nullptr, Tmm);

        feat_kernel<<<CH / 2, 256, 0, stream>>>(
            item_id + off, likes + off, views + off,
            seq + (size_t)off * HIST_L, item_emb, cate_emb, mm,
            ln_g, ln_b, se_W1, se_b1, se_W2, se_b2, xs);

        // xw (fields 2..5) = xs_field @ bi_W : M = CH*4, N = 128, K = 128
        dim3 gxw(CH * 4 / 64, 128 / 64);
        gemm_bt<2, 0, 64, 64, 0><<<gxw, 256, 0, stream>>>(
            xs, nullptr, bWt, xw, CH * 4, 128, 128, nullptr, nullptr);

        // h1 = relu(BN1(...)): fused pairs staging, compact K = 1920
        // MT=64 -> grid (CH/64)x8 = 1024 blocks = 4/CU (was 2/CU at MT=128)
        dim3 g1(CH / 64, 512 / 64);
        gemm_bt<1, 1, 64, 64, 0><<<g1, 256, 0, stream>>>(
            xs, xw, W1t, h1, CH, 512, 1920, S1, T1);

        // h2 = relu(BN2(h1 @ W2)): K = 512   (h2 overwrites xw - dead)
        dim3 g2(CH / 64, 256 / 64);
        gemm_bt<0, 1, 64, 64, 0><<<g2, 256, 0, stream>>>(
            h1, nullptr, W2t, h2, CH, 256, 512, S2, T2);

        head_kernel<<<CH / 4, 256, 0, stream>>>(h2, W3, b3, (float*)d_out + off);
    }
}

// Round 11
// 317.105 us; speedup vs baseline: 1.0443x; 1.0443x over previous
//
#include <hip/hip_runtime.h>
#include <hip/hip_bf16.h>

typedef __hip_bfloat16 bfloat;
typedef __bf16 bf16x8 __attribute__((ext_vector_type(8)));
typedef float f32x4 __attribute__((ext_vector_type(4)));

#define B_SZ   16384
#define E_DIM  128
#define HIST_L 50

// DTYPE MAP (rounds 0-4): inputs fp32, output fp32, internal bf16 for MFMA.
// WS DISCIPLINE (round 4): chunked batch, strictly inside ws_size
//   (ws in [31.37, 56.77) MB per rounds 5/7 ladder evidence).
// ROUND 10 pm: MT=64 REGRESSED (85->100us) despite occupancy 37->70% —
// halved MFMA-per-barrier and doubled B traffic. The binding resource is
// per-barrier DMA drain x barrier count, not wave residency.
// ROUND 11: revert MT=128/NT=64 (round-9 best) + BK=64 as TWO stride-32
// sub-tiles (As[2][128*32]) — each keeps the lane-contiguous layout
// global_load_lds requires ((l>>2)*64+(l&3)*16 == 16*l). Barriers halved:
// MLP1 60->30, MLP2 16->8, xw/mm 4->2. LDS 24KB, occupancy unchanged.

// compact pair tables (pp=0..9 <-> orig pairs (1,2),(1,3),(1,4),(1,5),
// (2,3),(2,4),(2,5),(3,4),(3,5),(4,5)); xs slot = I-1, xw slot = J-2.
#define IPACK 0x3221110000ULL
#define JPACK 0x3323213210ULL

__device__ __forceinline__ void gl_lds16(const void* g, void* l) {
    __builtin_amdgcn_global_load_lds(
        (const __attribute__((address_space(1))) unsigned int*)g,
        (__attribute__((address_space(3))) unsigned int*)l, 16, 0, 0);
}

__device__ __forceinline__ bf16x8 mul_bf16x8(bf16x8 a, bf16x8 b) {
    union { bf16x8 v; __hip_bfloat162 h[4]; } ua, ub, ur;
    ua.v = a; ub.v = b;
    #pragma unroll
    for (int i = 0; i < 4; ++i) ur.h[i] = __hmul2(ua.h[i], ub.h[i]);
    return ur.v;
}

// ---------------------------------------------------------------- features
// 256 threads = 2 batch rows per block. mm (post-bias fp32) precomputed.
__global__ __launch_bounds__(256) void feat_kernel(
    const int* __restrict__ item_id,
    const int* __restrict__ likes, const int* __restrict__ views,
    const int* __restrict__ seq,
    const float* __restrict__ item_emb, const float* __restrict__ cate_emb,
    const float* __restrict__ mm,
    const float* __restrict__ ln_g, const float* __restrict__ ln_b,
    const float* __restrict__ se_W1, const float* __restrict__ se_b1,
    const float* __restrict__ se_W2, const float* __restrict__ se_b2,
    bfloat* __restrict__ xs)
{
    const int tid = threadIdx.x;
    const int r   = tid >> 7;            // sub-row 0/1
    const int e   = tid & 127;
    const int b   = blockIdx.x * 2 + r;
    const int w   = tid >> 6;            // wave 0..3 (row = w>>1)

    __shared__ float redh[2][4][128];
    __shared__ int   seq_s[2][64];
    __shared__ float lnred[4], lnred2[4];
    __shared__ float zred[5][4];
    __shared__ float wsh[2][6];
    __shared__ int   cnt_s[2];

    if (e < 64) seq_s[r][e] = (e < HIST_L) ? seq[(size_t)b * HIST_L + e] : 0;
    __syncthreads();

    // long-latency gathers first
    const int iid = item_id[b];
    const float like_v = cate_emb[likes[b] * 128 + e];
    const float view_v = cate_emb[views[b] * 128 + e];
    const float item_raw = item_emb[(size_t)iid * 128 + e];
    const float item_v = iid ? item_raw : 0.f;
    const float acc = mm[(size_t)b * 128 + e];   // bias already added

    const int q   = e >> 5;
    const int l32 = e & 31;
    float4 hs = make_float4(0.f, 0.f, 0.f, 0.f);
    #pragma unroll
    for (int g = 0; g < 13; ++g) {
        int s = seq_s[r][g * 4 + q];
        const float4 v = *(const float4*)&item_emb[(size_t)s * 128 + l32 * 4];
        float m = (s != 0) ? 1.f : 0.f;
        hs.x = fmaf(v.x, m, hs.x);
        hs.y = fmaf(v.y, m, hs.y);
        hs.z = fmaf(v.z, m, hs.z);
        hs.w = fmaf(v.w, m, hs.w);
    }

    // LayerNorm reductions (per 2-wave row)
    {
        float v = acc;
        #pragma unroll
        for (int off = 32; off > 0; off >>= 1) v += __shfl_down(v, off, 64);
        if ((tid & 63) == 0) lnred[w] = v;
    }
    __syncthreads();
    const float mu = (lnred[2 * r] + lnred[2 * r + 1]) * (1.f / 128.f);
    const float d  = acc - mu;
    {
        float v = d * d;
        #pragma unroll
        for (int off = 32; off > 0; off >>= 1) v += __shfl_down(v, off, 64);
        if ((tid & 63) == 0) lnred2[w] = v;
    }
    redh[r][q][l32 * 4 + 0] = hs.x;
    redh[r][q][l32 * 4 + 1] = hs.y;
    redh[r][q][l32 * 4 + 2] = hs.z;
    redh[r][q][l32 * 4 + 3] = hs.w;
    if ((w & 1) == 0 && e < 64) {       // first wave of each row
        bool valid = (e < HIST_L) && (seq_s[r][e] != 0);
        unsigned long long m = __ballot(valid);
        if (e == 0) cnt_s[r] = (int)__popcll(m);
    }
    __syncthreads();
    const float var = (lnred2[2 * r] + lnred2[2 * r + 1]) * (1.f / 128.f);
    float xmm = d * rsqrtf(var + 1e-5f) * ln_g[e] + ln_b[e];
    xmm = fmaxf(xmm, 0.f);

    const int cnt = cnt_s[r] > 0 ? cnt_s[r] : 1;
    const float hist_v = (redh[r][0][e] + redh[r][1][e] +
                          redh[r][2][e] + redh[r][3][e]) / (float)cnt;

    // SENet z means: 5 sums, one barrier
    {
        float s1 = like_v, s2 = view_v, s3 = item_v, s4 = xmm, s5 = hist_v;
        #pragma unroll
        for (int off = 32; off > 0; off >>= 1) {
            s1 += __shfl_down(s1, off, 64);
            s2 += __shfl_down(s2, off, 64);
            s3 += __shfl_down(s3, off, 64);
            s4 += __shfl_down(s4, off, 64);
            s5 += __shfl_down(s5, off, 64);
        }
        if ((tid & 63) == 0) {
            zred[0][w] = s1; zred[1][w] = s2; zred[2][w] = s3;
            zred[3][w] = s4; zred[4][w] = s5;
        }
    }
    __syncthreads();

    if (e == 0) {
        float z[6];
        z[0] = 0.f;
        #pragma unroll
        for (int f = 1; f < 6; ++f)
            z[f] = (zred[f - 1][2 * r] + zred[f - 1][2 * r + 1]) * (1.f / 128.f);
        float a[3];
        #pragma unroll
        for (int j = 0; j < 3; ++j) {
            float s = se_b1[j];
            #pragma unroll
            for (int f = 0; f < 6; ++f) s += z[f] * se_W1[f * 3 + j];
            a[j] = fmaxf(s, 0.f);
        }
        #pragma unroll
        for (int f = 0; f < 6; ++f) {
            float s = se_b2[f];
            #pragma unroll
            for (int j = 0; j < 3; ++j) s += a[j] * se_W2[j * 6 + f];
            wsh[r][f] = 1.f / (1.f + expf(-s));
        }
    }
    __syncthreads();

    bfloat* xrow = xs + (size_t)b * 640;      // fields 1..5 at slots 0..4
    xrow[0 * 128 + e] = __float2bfloat16(like_v * wsh[r][1]);
    xrow[1 * 128 + e] = __float2bfloat16(view_v * wsh[r][2]);
    xrow[2 * 128 + e] = __float2bfloat16(item_v * wsh[r][3]);
    xrow[3 * 128 + e] = __float2bfloat16(xmm    * wsh[r][4]);
    xrow[4 * 128 + e] = __float2bfloat16(hist_v * wsh[r][5]);
}

// ---------------------------------------------------------------- transposes
__global__ __launch_bounds__(256) void transpose_f32_bf16(
    const float* __restrict__ in, bfloat* __restrict__ out, int K, int N)
{
    int idx = blockIdx.x * 256 + threadIdx.x;
    if (idx < K * N) {
        int k = idx / N, n = idx % N;
        out[(size_t)n * K + k] = __float2bfloat16(in[idx]);
    }
}

// W1 compact transpose: W1t[n][kk] = W1[orig(kk)][n], orig = kk + (kk<640?128:768)
__global__ __launch_bounds__(256) void transpose_W1c(
    const float* __restrict__ W1, bfloat* __restrict__ W1t)
{
    int idx = blockIdx.x * 256 + threadIdx.x;
    if (idx < 512 * 1920) {
        int n = idx / 1920, kk = idx % 1920;
        int orig = kk + (kk < 640 ? 128 : 768);
        W1t[idx] = __float2bfloat16(W1[(size_t)orig * 512 + n]);
    }
}

// BN folding + mm-bias copy.
__global__ __launch_bounds__(256) void bn_pre(
    const float* __restrict__ lb1, const float* __restrict__ g1,
    const float* __restrict__ bb1, const float* __restrict__ rm1,
    const float* __restrict__ rv1,
    const float* __restrict__ lb2, const float* __restrict__ g2,
    const float* __restrict__ bb2, const float* __restrict__ rm2,
    const float* __restrict__ rv2,
    const float* __restrict__ mm_b,
    float* __restrict__ S1, float* __restrict__ T1,
    float* __restrict__ S2, float* __restrict__ T2,
    float* __restrict__ Tmm)
{
    int j = blockIdx.x * 256 + threadIdx.x;
    if (j < 512) {
        float s = g1[j] * rsqrtf(rv1[j] + 1e-5f);
        S1[j] = s;
        T1[j] = (lb1[j] - rm1[j]) * s + bb1[j];
    } else if (j < 768) {
        int k = j - 512;
        float s = g2[k] * rsqrtf(rv2[k] + 1e-5f);
        S2[k] = s;
        T2[k] = (lb2[k] - rm2[k]) * s + bb2[k];
    } else if (j < 896) {
        Tmm[j - 768] = mm_b[j - 768];
    }
}

// ---------------------------------------------------------------- MFMA GEMM
// C(M,N) = A(M,K) @ Bt(N,K)^T.  Tile MT x NT, BK=64 via TWO stride-32
// sub-tiles (each lane-contiguous for global_load_lds). 256 thr = 4 waves 2x2.
// MODE 0: plain bf16 A (DMA). MODE 1: fused MLP1 (xs region DMA, pair region
// __hmul2 product, K=1920). MODE 2: xw rows from xs (DMA). MODE 3: fp32 cvt.
// EPI 0: raw. EPI 1: relu(acc*S+T). EPI 2: acc+T. F32OUT: write fp32.
// K must be a multiple of 64 (128/512/1920 all are; pair boundary 640%64==0,
// sub-chunk kk=kt+32 never crosses it).
template<int MODE, int EPI, int MT, int NT, int F32OUT>
__global__ __launch_bounds__(256) void gemm_bt(
    const void* __restrict__ A, const bfloat* __restrict__ A2,
    const bfloat* __restrict__ Bt, void* __restrict__ C,
    int M, int N, int K,
    const float* __restrict__ S, const float* __restrict__ T)
{
    __shared__ __align__(16) short As[2][MT * 32];
    __shared__ __align__(16) short Bs[2][NT * 32];

    const int tid  = threadIdx.x;
    const int bm   = blockIdx.x * MT;
    const int bn   = blockIdx.y * NT;
    const int wave = tid >> 6;
    const int lane = tid & 63;
    const int wm   = (wave >> 1) * (MT / 2);
    const int wn   = (wave & 1) * (NT / 2);
    const int AF   = MT / 32;
    const int BF   = NT / 32;

    const short* Ag  = (const short*)A;
    const short* A2g = (const short*)A2;
    const short* Bg  = (const short*)Bt;

    f32x4 acc[MT / 32][NT / 32];
    #pragma unroll
    for (int i = 0; i < AF; ++i)
        #pragma unroll
        for (int j = 0; j < BF; ++j)
            acc[i][j] = (f32x4){0.f, 0.f, 0.f, 0.f};

    const int srow = tid >> 2;          // 0..63
    const int skc  = (tid & 3) * 8;     // 16B chunk within 32-k sub-tile

    for (int kt = 0; kt < K; kt += 64) {
        __syncthreads();
        #pragma unroll
        for (int h = 0; h < 2; ++h) {
            const int kk = kt + h * 32;
            // ---- A staging (MT rows; dest = wave base + lane*16B) ----
            #pragma unroll
            for (int r = 0; r < MT / 64; ++r) {
                int row = srow + r * 64;
                short* dst = &As[h][row * 32 + skc];
                if (MODE == 1) {
                    long rb = (long)(bm + row);
                    if (kk < 640) {
                        gl_lds16(&Ag[rb * 640 + kk + skc], dst);
                    } else {
                        int pp  = (kk - 640) >> 7;        // wave-uniform
                        int isl = (int)((IPACK >> (4 * pp)) & 15);
                        int jsl = (int)((JPACK >> (4 * pp)) & 15);
                        int e0  = ((kk - 640) & 127) + skc;
                        bf16x8 a = *(const bf16x8*)&Ag [rb * 640 + isl * 128 + e0];
                        bf16x8 b = *(const bf16x8*)&A2g[rb * 512 + jsl * 128 + e0];
                        *(bf16x8*)dst = mul_bf16x8(a, b);
                    }
                } else if (MODE == 2) {
                    int gr = bm + row;
                    gl_lds16(&Ag[((long)(gr >> 2)) * 640 +
                                 ((gr & 3) + 1) * 128 + kk + skc], dst);
                } else if (MODE == 3) {
                    const float* Af = (const float*)A;
                    long aoff = (long)(bm + row) * K + kk + skc;
                    float4 f0 = *(const float4*)&Af[aoff];
                    float4 f1 = *(const float4*)&Af[aoff + 4];
                    union { bf16x8 v; unsigned short s[8]; } u;
                    u.s[0] = __bfloat16_as_ushort(__float2bfloat16(f0.x));
                    u.s[1] = __bfloat16_as_ushort(__float2bfloat16(f0.y));
                    u.s[2] = __bfloat16_as_ushort(__float2bfloat16(f0.z));
                    u.s[3] = __bfloat16_as_ushort(__float2bfloat16(f0.w));
                    u.s[4] = __bfloat16_as_ushort(__float2bfloat16(f1.x));
                    u.s[5] = __bfloat16_as_ushort(__float2bfloat16(f1.y));
                    u.s[6] = __bfloat16_as_ushort(__float2bfloat16(f1.z));
                    u.s[7] = __bfloat16_as_ushort(__float2bfloat16(f1.w));
                    *(bf16x8*)dst = u.v;
                } else {
                    gl_lds16(&Ag[(long)(bm + row) * K + kk + skc], dst);
                }
            }
            // ---- B staging (NT rows) ----
            #pragma unroll
            for (int r = 0; r < NT / 64; ++r) {
                int row = srow + r * 64;
                gl_lds16(&Bg[(long)(bn + row) * K + kk + skc],
                         &Bs[h][row * 32 + skc]);
            }
        }
        __syncthreads();

        const int koff  = (lane >> 4) * 8;
        const int rbase = lane & 15;
        #pragma unroll
        for (int h = 0; h < 2; ++h) {
            bf16x8 af[MT / 32], bfr[NT / 32];
            #pragma unroll
            for (int mt = 0; mt < AF; ++mt)
                af[mt] = *(const bf16x8*)
                    &As[h][(wm + mt * 16 + rbase) * 32 + koff];
            #pragma unroll
            for (int nt = 0; nt < BF; ++nt)
                bfr[nt] = *(const bf16x8*)
                    &Bs[h][(wn + nt * 16 + rbase) * 32 + koff];
            #pragma unroll
            for (int mt = 0; mt < AF; ++mt)
                #pragma unroll
                for (int nt = 0; nt < BF; ++nt)
                    acc[mt][nt] = __builtin_amdgcn_mfma_f32_16x16x32_bf16(
                        af[mt], bfr[nt], acc[mt][nt], 0, 0, 0);
        }
    }

    // epilogue: C/D layout col = lane&15, row = (lane>>4)*4 + i
    const int col0 = lane & 15;
    const int row0 = (lane >> 4) * 4;
    #pragma unroll
    for (int nt = 0; nt < BF; ++nt) {
        int col = bn + wn + nt * 16 + col0;
        float s = 1.f, t = 0.f;
        if (EPI) { s = (EPI == 1) ? S[col] : 1.f; t = T[col]; }
        #pragma unroll
        for (int mt = 0; mt < AF; ++mt) {
            #pragma unroll
            for (int i = 0; i < 4; ++i) {
                int row = bm + wm + mt * 16 + row0 + i;
                float v = acc[mt][nt][i];
                if (EPI == 1) v = fmaxf(v * s + t, 0.f);
                if (EPI == 2) v = v + t;
                if (F32OUT) ((float*)C)[(size_t)row * N + col] = v;
                else ((bfloat*)C)[(size_t)row * N + col] = __float2bfloat16(v);
            }
        }
    }
}

// ---------------------------------------------------------------- head
__global__ __launch_bounds__(256) void head_kernel(
    const bfloat* __restrict__ h2, const float* __restrict__ W3,
    const float* __restrict__ b3, float* __restrict__ out)
{
    int lane = threadIdx.x & 63;
    int row  = blockIdx.x * 4 + (threadIdx.x >> 6);
    float acc = 0.f;
    #pragma unroll
    for (int i = 0; i < 4; ++i)
        acc += __bfloat162float(h2[(size_t)row * 256 + i * 64 + lane]) *
               W3[i * 64 + lane];
    #pragma unroll
    for (int off = 32; off > 0; off >>= 1) acc += __shfl_down(acc, off, 64);
    if (lane == 0) {
        float l = acc + b3[0];
        out[row] = 1.f / (1.f + expf(-l));
    }
}

// ---------------------------------------------------------------- launch
extern "C" void kernel_launch(void* const* d_in, const int* in_sizes, int n_in,
                              void* d_out, int out_size, void* d_ws, size_t ws_size,
                              hipStream_t stream) {
    const int*   item_id = (const int*)  d_in[0];
    const float* d128    = (const float*)d_in[1];
    const int*   likes   = (const int*)  d_in[2];
    const int*   views   = (const int*)  d_in[3];
    const int*   seq     = (const int*)  d_in[4];
    const float* item_emb= (const float*)d_in[5];
    const float* cate_emb= (const float*)d_in[6];
    const float* mm_W    = (const float*)d_in[7];
    const float* mm_b    = (const float*)d_in[8];
    const float* ln_g    = (const float*)d_in[9];
    const float* ln_b    = (const float*)d_in[10];
    const float* se_W1   = (const float*)d_in[11];
    const float* se_b1   = (const float*)d_in[12];
    const float* se_W2   = (const float*)d_in[13];
    const float* se_b2   = (const float*)d_in[14];
    const float* bi_W    = (const float*)d_in[15];
    const float* W1      = (const float*)d_in[16];
    const float* b1      = (const float*)d_in[17];
    const float* bn1_g   = (const float*)d_in[18];
    const float* bn1_b   = (const float*)d_in[19];
    const float* bn1_rm  = (const float*)d_in[20];
    const float* bn1_rv  = (const float*)d_in[21];
    const float* W2      = (const float*)d_in[22];
    const float* b2      = (const float*)d_in[23];
    const float* bn2_g   = (const float*)d_in[24];
    const float* bn2_b   = (const float*)d_in[25];
    const float* bn2_rm  = (const float*)d_in[26];
    const float* bn2_rv  = (const float*)d_in[27];
    const float* W3      = (const float*)d_in[28];
    const float* b3      = (const float*)d_in[29];

    // --------- workspace (ws_size in [31.4, 56.8) MB per rounds 5/7) --------
    // fixed: W1t 1,966,080 | W2t 262,144 | bWt 32,768 | mmWt 32,768 |
    //        S1/T1 4,096 | S2/T2 2,048 | Tmm 512  = 2,300,416 B
    // per-row 3328 B: xs 1280 | xw 1024 | h1 1024. h2 aliases xw;
    // mm (fp32, 512 B/row) aliases h1 (consumed by feat before h1 written).
    const size_t fixed = 2300416;
    int CH = 1024;
    if      (fixed + (size_t)16384 * 3328 <= ws_size) CH = 16384;
    else if (fixed + (size_t)8192  * 3328 <= ws_size) CH = 8192;
    else if (fixed + (size_t)4096  * 3328 <= ws_size) CH = 4096;
    else if (fixed + (size_t)2048  * 3328 <= ws_size) CH = 2048;

    char* ws = (char*)d_ws;
    bfloat* W1t = (bfloat*)(ws);                 // 1,966,080
    bfloat* W2t = (bfloat*)(ws + 1966080);       //   262,144
    bfloat* bWt = (bfloat*)(ws + 2228224);       //    32,768
    bfloat* mmWt= (bfloat*)(ws + 2260992);       //    32,768
    float*  S1  = (float*) (ws + 2293760);       //     2,048
    float*  T1  = (float*) (ws + 2295808);       //     2,048
    float*  S2  = (float*) (ws + 2297856);       //     1,024
    float*  T2  = (float*) (ws + 2298880);       //     1,024
    float*  Tmm = (float*) (ws + 2299904);       //       512 -> 2,300,416
    bfloat* xs  = (bfloat*)(ws + fixed);                        // CH*1280 B
    bfloat* xw  = (bfloat*)(ws + fixed + (size_t)CH * 1280);    // CH*1024 B
    bfloat* h1  = (bfloat*)(ws + fixed + (size_t)CH * 2304);    // CH*1024 B
    bfloat* h2  = xw;                                           // alias
    float*  mm  = (float*)h1;                                   // alias

    transpose_W1c<<<(512 * 1920 + 255) / 256, 256, 0, stream>>>(W1, W1t);
    transpose_f32_bf16<<<(512 * 256 + 255) / 256, 256, 0, stream>>>(W2, W2t, 512, 256);
    transpose_f32_bf16<<<(128 * 128 + 255) / 256, 256, 0, stream>>>(bi_W, bWt, 128, 128);
    transpose_f32_bf16<<<(128 * 128 + 255) / 256, 256, 0, stream>>>(mm_W, mmWt, 128, 128);
    bn_pre<<<4, 256, 0, stream>>>(b1, bn1_g, bn1_b, bn1_rm, bn1_rv,
                                  b2, bn2_g, bn2_b, bn2_rm, bn2_rv,
                                  mm_b, S1, T1, S2, T2, Tmm);

    for (int off = 0; off < B_SZ; off += CH) {
        // mm = d128 @ mm_W + b  (fp32 out; aliases h1, consumed by feat)
        dim3 gmm(CH / 128, 128 / 64);
        gemm_bt<3, 2, 128, 64, 1><<<gmm, 256, 0, stream>>>(
            d128 + (size_t)off * 128, nullptr, mmWt, mm,
            CH, 128, 128, nullptr, Tmm);

        feat_kernel<<<CH / 2, 256, 0, stream>>>(
            item_id + off, likes + off, views + off,
            seq + (size_t)off * HIST_L, item_emb, cate_emb, mm,
            ln_g, ln_b, se_W1, se_b1, se_W2, se_b2, xs);

        // xw (fields 2..5) = xs_field @ bi_W : M = CH*4, N = 128, K = 128
        dim3 gxw(CH * 4 / 128, 128 / 64);
        gemm_bt<2, 0, 128, 64, 0><<<gxw, 256, 0, stream>>>(
            xs, nullptr, bWt, xw, CH * 4, 128, 128, nullptr, nullptr);

        // h1 = relu(BN1(...)): fused pairs staging, K = 1920, 30 barriers
        dim3 g1(CH / 128, 512 / 64);
        gemm_bt<1, 1, 128, 64, 0><<<g1, 256, 0, stream>>>(
            xs, xw, W1t, h1, CH, 512, 1920, S1, T1);

        // h2 = relu(BN2(h1 @ W2)): K = 512   (h2 overwrites xw - dead)
        dim3 g2(CH / 128, 256 / 64);
        gemm_bt<0, 1, 128, 64, 0><<<g2, 256, 0, stream>>>(
            h1, nullptr, W2t, h2, CH, 256, 512, S2, T2);

        head_kernel<<<CH / 4, 256, 0, stream>>>(h2, W3, b3, (float*)d_out + off);
    }
}